// Round 1
// baseline (141.190 us; speedup 1.0000x reference)
//
#include <hip/hip_runtime.h>

#define POINTS 120
#define GROUPS 4
#define HWSZ 65536          // 256*256
#define NB 8
#define NC 64
#define NTOT (NB*NC*HWSZ)   // 33554432
#define NGRP (NTOT/GROUPS)  // 8388608 elements per group slice

// Workspace layout (32-bit words):
// [0,480)    hist counts (uint), 4 groups x 120 bins
// [480,484)  min keys (ordered uint)
// [484,488)  max keys (ordered uint)
// [488,492)  dmin per group (float)
// [492,496)  width per group (float)
// [496,976)  accum (float) 4x120
// [976,1456) frame_theta (float) 4x120
// [1456,1936) frame_velo (float) 4x120

__device__ __forceinline__ unsigned ord_enc(float f) {
    unsigned u = __float_as_uint(f);
    return (u & 0x80000000u) ? ~u : (u | 0x80000000u);
}
__device__ __forceinline__ float ord_dec(unsigned k) {
    unsigned u = (k & 0x80000000u) ? (k ^ 0x80000000u) : ~k;
    return __uint_as_float(u);
}

__global__ __launch_bounds__(512) void k_init(unsigned* ws) {
    int t = threadIdx.x;
    if (t < 480) ws[t] = 0u;
    else if (t < 484) ws[t] = 0xFFFFFFFFu;   // min sentinel (ordered keys)
    else if (t < 488) ws[t] = 0u;            // max sentinel
}

// grid = 1024 blocks, each covers 32768 contiguous elements (half a channel plane)
__global__ __launch_bounds__(256) void k_minmax(const float* __restrict__ data,
                                                const float* __restrict__ ct_p,
                                                unsigned* __restrict__ ws) {
    const float ct = ct_p[0];
    const int g = (blockIdx.x >> 1) & 3;   // plane = blockIdx/2; group = plane & 3 = channel & 3
    const size_t base = (size_t)blockIdx.x * 32768;
    const float4* p = (const float4*)(data + base);
    float mn = 3.0e38f, mx = -3.0e38f;
    #pragma unroll 4
    for (int it = 0; it < 32; ++it) {
        float4 v = p[it * 256 + threadIdx.x];
        v.x *= ct; v.y *= ct; v.z *= ct; v.w *= ct;
        mn = fminf(mn, fminf(fminf(v.x, v.y), fminf(v.z, v.w)));
        mx = fmaxf(mx, fmaxf(fmaxf(v.x, v.y), fmaxf(v.z, v.w)));
    }
    for (int off = 32; off; off >>= 1) {
        mn = fminf(mn, __shfl_xor(mn, off));
        mx = fmaxf(mx, __shfl_xor(mx, off));
    }
    __shared__ float smn[4], smx[4];
    int wid = threadIdx.x >> 6;
    if ((threadIdx.x & 63) == 0) { smn[wid] = mn; smx[wid] = mx; }
    __syncthreads();
    if (threadIdx.x == 0) {
        mn = fminf(fminf(smn[0], smn[1]), fminf(smn[2], smn[3]));
        mx = fmaxf(fmaxf(smx[0], smx[1]), fmaxf(smx[2], smx[3]));
        atomicMin(&ws[480 + g], ord_enc(mn));
        atomicMax(&ws[484 + g], ord_enc(mx));
    }
}

// grid = 1024 blocks, same partitioning as k_minmax
__global__ __launch_bounds__(256) void k_hist(const float* __restrict__ data,
                                              const float* __restrict__ ct_p,
                                              unsigned* __restrict__ ws) {
    const float ct = ct_p[0];
    const int g = (blockIdx.x >> 1) & 3;
    __shared__ unsigned h[POINTS];
    for (int i = threadIdx.x; i < POINTS; i += 256) h[i] = 0u;
    const float dmin = ord_dec(ws[480 + g]);
    const float dmax = ord_dec(ws[484 + g]);
    const float width = (dmax - dmin) / (float)POINTS;
    __syncthreads();
    const size_t base = (size_t)blockIdx.x * 32768;
    const float4* p = (const float4*)(data + base);
    for (int it = 0; it < 32; ++it) {
        float4 v = p[it * 256 + threadIdx.x];
        float a[4] = {v.x, v.y, v.z, v.w};
        #pragma unroll
        for (int j = 0; j < 4; ++j) {
            float d = a[j] * ct;
            int b = (int)floorf((d - dmin) / width);
            b = min(max(b, 0), POINTS - 1);
            atomicAdd(&h[b], 1u);
        }
    }
    __syncthreads();
    for (int i = threadIdx.x; i < POINTS; i += 256) atomicAdd(&ws[g * POINTS + i], h[i]);
}

// single block, 128 threads: build accum + warped param curves
__global__ __launch_bounds__(128) void k_curves(const float* __restrict__ params,
                                                unsigned* __restrict__ wsu) {
    float* wsf = (float*)wsu;
    __shared__ float acc[GROUPS][POINTS];
    const int t = threadIdx.x;
    if (t < GROUPS) {
        const int g = t;
        float dmin = ord_dec(wsu[480 + g]);
        float dmax = ord_dec(wsu[484 + g]);
        float width = (dmax - dmin) / (float)POINTS;
        wsf[488 + g] = dmin;
        wsf[492 + g] = width;
        float c = 0.f;
        for (int k = 0; k < POINTS; ++k) {
            float prob = (float)wsu[g * POINTS + k] / (float)NGRP;
            c += prob;
            float a = c * (float)(POINTS - 1);
            acc[g][k] = a;
            wsf[496 + g * POINTS + k] = a;
        }
    }
    __syncthreads();
    if (t < POINTS) {
        float v = (float)t;   // xnew
        for (int g = 0; g < GROUPS; ++g) {
            int cnt = 0;
            for (int k = 0; k < POINTS; ++k) cnt += (acc[g][k] < v) ? 1 : 0;
            int ind = min(max(cnt - 1, 0), POINTS - 2);
            float x0 = acc[g][ind], x1 = acc[g][ind + 1];
            float tt = (v - x0) / (x1 - x0);
            const float* th = params + g * POINTS;
            const float* ve = params + GROUPS * POINTS + g * POINTS;
            wsf[976  + g * POINTS + t] = th[ind] + tt * (th[ind + 1] - th[ind]);
            wsf[1456 + g * POINTS + t] = ve[ind] + tt * (ve[ind + 1] - ve[ind]);
        }
    }
}

// grid-stride over m in [0, NTOT/4); each thread produces out[4m..4m+3] as one float4
__global__ __launch_bounds__(256) void k_apply(const float* __restrict__ data,
                                               const float* __restrict__ ct_p,
                                               const float* __restrict__ st_p,
                                               const unsigned* __restrict__ wsu,
                                               float4* __restrict__ out) {
    const float* wsf = (const float*)wsu;
    __shared__ float s_acc[GROUPS * POINTS];
    __shared__ float s_ft[GROUPS * POINTS];
    __shared__ float s_fv[GROUPS * POINTS];
    __shared__ float s_dw[8];   // dmin[4], width[4]
    for (int i = threadIdx.x; i < GROUPS * POINTS; i += 256) {
        s_acc[i] = wsf[496 + i];
        s_ft[i]  = wsf[976 + i];
        s_fv[i]  = wsf[1456 + i];
    }
    if (threadIdx.x < 8) s_dw[threadIdx.x] = wsf[488 + threadIdx.x];
    __syncthreads();

    const float ct = ct_p[0], st = st_p[0];
    const int M = NTOT / 4;
    for (int m = blockIdx.x * 256 + threadIdx.x; m < M; m += gridDim.x * 256) {
        int b  = m >> 20;          // 16*65536 = 2^20 m's per batch
        int cp = (m >> 16) & 15;   // channel-within-group index
        int hw = m & 65535;
        size_t base = ((size_t)(b * 64 + cp * 4) << 16) + hw;
        float r[4];
        #pragma unroll
        for (int g = 0; g < 4; ++g) {
            float v = data[base + ((size_t)g << 16)] * ct;
            float dmin = s_dw[g], width = s_dw[4 + g];
            const float* acc = s_acc + g * POINTS;
            // ind = clip(searchsorted(centers, v, 'left')-1, 0, 118); continuous, so floor form is safe
            float u = (v - dmin) / width - 0.5f;
            int ind = min(max((int)floorf(u), 0), POINTS - 2);
            float c0 = dmin + width * ((float)ind + 0.5f);
            float c1 = dmin + width * ((float)ind + 1.5f);
            float a0 = acc[ind], a1 = acc[ind + 1];
            float index = a0 + (v - c0) / (c1 - c0) * (a1 - a0);
            int beg = min(max((int)floorf(index), 0), POINTS - 1);
            float pos = index - (float)beg;
            int end = min(beg + 1, POINTS - 1);
            float theta = (1.f - pos) * s_ft[g * POINTS + beg] + pos * s_ft[g * POINTS + end];
            float velo  = (1.f - pos) * s_fv[g * POINTS + beg] + pos * s_fv[g * POINTS + end];
            float ds = velo * 0.01f;
            float sth, cth;
            __sincosf(theta, &sth, &cth);
            r[g] = (v * (1.f + ds * sth) + ds * cth) * st;
        }
        float4 o; o.x = r[0]; o.y = r[1]; o.z = r[2]; o.w = r[3];
        out[m] = o;
    }
}

extern "C" void kernel_launch(void* const* d_in, const int* in_sizes, int n_in,
                              void* d_out, int out_size, void* d_ws, size_t ws_size,
                              hipStream_t stream) {
    const float* data = (const float*)d_in[0];
    const float* params = (const float*)d_in[1];
    const float* ct = (const float*)d_in[2];
    const float* st = (const float*)d_in[3];
    unsigned* ws = (unsigned*)d_ws;
    float4* out = (float4*)d_out;

    hipLaunchKernelGGL(k_init, dim3(1), dim3(512), 0, stream, ws);
    hipLaunchKernelGGL(k_minmax, dim3(1024), dim3(256), 0, stream, data, ct, ws);
    hipLaunchKernelGGL(k_hist, dim3(1024), dim3(256), 0, stream, data, ct, ws);
    hipLaunchKernelGGL(k_curves, dim3(1), dim3(128), 0, stream, params, ws);
    hipLaunchKernelGGL(k_apply, dim3(4096), dim3(256), 0, stream, data, ct, st, ws, out);
}